// Round 9
// baseline (239.462 us; speedup 1.0000x reference)
//
#include <hip/hip_runtime.h>
#include <hip/hip_bf16.h>

typedef __hip_bfloat16 bf16;
typedef short v8s __attribute__((ext_vector_type(8)));
typedef float v4f __attribute__((ext_vector_type(4)));
typedef unsigned int u32;

#define BFLO(u) __uint_as_float((u) << 16)
#define BFHI(u) __uint_as_float((u) & 0xffff0000u)

#define CH 4096        // edges per distribute block (293 dist blocks)
#define MAXNB 800      // >= 2 * ceil(N/256) = 782
#define CAP 2048       // fixed bucket capacity: mean 1534, sigma ~39 -> 13-sigma margin

// Derive index stride in-block: int64 LE with values < 2^31 has zero odd slots.
__device__ __forceinline__ int block_stride(const int* e0, int E, int* sm) {
    int t = threadIdx.x;
    if (t == 0) *sm = 0;
    __syncthreads();
    int nz = 0;
    for (int i = t; i < 2048; i += 256) {
        int slot = 2 * i + 1;
        if (slot < 2 * E) nz |= (e0[slot] != 0);
    }
    if (nz) atomicOr(sm, 1);
    __syncthreads();
    return *sm ? 1 : 2;
}

// ---------------- fused front+dist: edge distribute (FIRST) | cvt | weight prep ----------------
// dist blocks first so their latency phase overlaps cvt's BW phase; dist uses
// two-pass LDS reserve -> direct global scatter (no scan/staging/copy loop).

__global__ __launch_bounds__(256) void frontdist_kernel(const float4* __restrict__ x4,
                                                        uint4* __restrict__ Ab4,
                                                        const float* __restrict__ Wrel,
                                                        const float* __restrict__ Wself,
                                                        const float* __restrict__ convw,
                                                        const float* __restrict__ convb,
                                                        bf16* __restrict__ B1T,
                                                        bf16* __restrict__ B2T,
                                                        float* __restrict__ cbf,
                                                        const int* __restrict__ e0,
                                                        const int* __restrict__ e1,
                                                        int* __restrict__ gcur,
                                                        unsigned int* __restrict__ esorted,
                                                        int N, int E, int nbrr,
                                                        int chBlocks, int cvtBlocks) {
    int b = blockIdx.x;
    if (b < chBlocks) {
        // ---- distribute: two-pass LDS reserve -> direct global scatter ----
        // record = src (17b) | tgt_local (8b) << 17
        __shared__ int hist[MAXNB], lcur[MAXNB], runbase[MAXNB];
        __shared__ int smf;
        int st = block_stride(e0, E, &smf);
        int NB = 2 * nbrr;
        int t = threadIdx.x;
        for (int i = t; i < NB; i += 256) { hist[i] = 0; lcur[i] = 0; }
        __syncthreads();
        long base = (long)b * CH;
        unsigned int rec[CH / 256]; short bk[CH / 256];
#pragma unroll
        for (int j = 0; j < CH / 256; ++j) {
            long e = base + j * 256 + t;
            if (e < 2 * (long)E) {
                int r = e >= E;
                long idx = r ? e - E : e;
                const int* ei = r ? e1 : e0;
                int src = ei[(size_t)idx * st];
                int tgt = ei[(size_t)(E + idx) * st];
                bk[j] = (short)(r * nbrr + (tgt >> 8));
                rec[j] = (unsigned int)src | ((unsigned int)(tgt & 255) << 17);
                atomicAdd(&hist[bk[j]], 1);
            } else bk[j] = -1;
        }
        __syncthreads();
        // reserve contiguous run per touched bucket (gcur zeroed by memset)
        for (int i = t; i < NB; i += 256)
            if (hist[i]) runbase[i] = i * CAP + atomicAdd(&gcur[i], hist[i]);
        __syncthreads();
        // direct scatter: rank within run via LDS atomic, store straight to global
#pragma unroll
        for (int j = 0; j < CH / 256; ++j) if (bk[j] >= 0) {
            int p = atomicAdd(&lcur[bk[j]], 1);
            esorted[runbase[bk[j]] + p] = rec[j];
        }
    } else if (b < chBlocks + cvtBlocks) {
        // ---- x -> bf16 into Ab cols 256:384, 32B/thread ----
        int i = (b - chBlocks) * 256 + threadIdx.x;
        if (i >= N * 16) return;
        int n = i >> 4, g2 = i & 15;
        float4 f0 = x4[2 * i], f1 = x4[2 * i + 1];
        union { uint4 u; bf16 h[8]; } o;
        o.h[0] = __float2bfloat16(f0.x); o.h[1] = __float2bfloat16(f0.y);
        o.h[2] = __float2bfloat16(f0.z); o.h[3] = __float2bfloat16(f0.w);
        o.h[4] = __float2bfloat16(f1.x); o.h[5] = __float2bfloat16(f1.y);
        o.h[6] = __float2bfloat16(f1.z); o.h[7] = __float2bfloat16(f1.w);
        Ab4[(size_t)n * 48 + 32 + g2] = o.u;
    } else {
        // ---- weight prep ----
        int i = (b - chBlocks - cvtBlocks) * 256 + threadIdx.x;
        if (i < 49152) {
            int co = i / 384, k = i % 384;
            float v;
            if (k < 128)      v = Wrel[co * 128 + k];
            else if (k < 256) v = Wrel[16384 + co * 128 + (k - 128)];
            else              v = Wself[co * 128 + (k - 256)];
            B1T[i] = __float2bfloat16(v);
        } else if (i < 98304) {
            int j = i - 49152;
            int co = j / 384, k = j % 384, kk = k >> 7, ci = k & 127;
            B2T[j] = __float2bfloat16(convw[co * 384 + ci * 3 + kk]);
        } else if (i < 98432) {
            int c = i - 98304;
            cbf[c] = convb[c];
        }
    }
}

// ---------------- fused csr+gather: per-HALF-bucket LDS sort -> direct gather-reduce ----------------
// R8 post-mortem: 782 blocks = 3.05/CU grid-capped, and each 16-lane group
// walked 16 nodes serially (dependent gather-sum chains) -> latency-bound.
// Split: one block per half-bucket (128 nodes): 1564 blocks (~6.1/CU,
// 24 waves/CU), serial chain halved to 8 nodes/group. Each half-block reads
// the full bucket record list (L2-hot, +12MB total) and filters by
// tgt_local bit 7 with atomic compaction; 128-bin sort; same inner loop.

__global__ __launch_bounds__(256) void csrgather_kernel(const unsigned int* __restrict__ esorted,
                                                        const int* __restrict__ gcur,
                                                        uint4* __restrict__ Ab4, int N, int nbrr) {
    __shared__ unsigned int rec_l[CAP];
    __shared__ int esrc_l[CAP];
    __shared__ int hist[256], lcur[256], tsum[256];
    __shared__ int nloc;
    int b = blockIdx.x;           // b = bucket*2 + half
    int bb = b >> 1, hf = b & 1;
    int r = bb >= nbrr;
    int g = r ? bb - nbrr : bb;
    int t = threadIdx.x;
    int s0 = bb * CAP;
    int ne = gcur[bb]; ne = (ne > CAP) ? CAP : ne;
    hist[t] = 0;
    if (t == 0) nloc = 0;
    __syncthreads();
    // filter + compact this half's records; histogram 128 bins
    for (int i = t; i < ne; i += 256) {
        unsigned int rec = esorted[s0 + i];
        int tl = (rec >> 17) & 255;
        if ((tl >> 7) == hf) {
            int p = atomicAdd(&nloc, 1);
            rec_l[p] = rec;
            atomicAdd(&hist[tl & 127], 1);
        }
    }
    __syncthreads();
    int nh = nloc;
    int h = hist[t];              // t >= 128 sees 0
    tsum[t] = h; __syncthreads();
    for (int d = 1; d < 256; d <<= 1) {
        int add = (t >= d) ? tsum[t - d] : 0;
        __syncthreads(); tsum[t] += add; __syncthreads();
    }
    lcur[t] = tsum[t] - h;   // exclusive start
    __syncthreads();
    for (int i = t; i < nh; i += 256) {
        unsigned int rec = rec_l[i];
        int p = atomicAdd(&lcur[(rec >> 17) & 127], 1);
        esrc_l[p] = rec & 0x1FFFF;
    }
    __syncthreads();
    // gather: 16-lane group per node, 8 nodes per group, unroll-8 uint4 rows
    int grp = t >> 4, lane = t & 15;
    for (int it = 0; it < 8; ++it) {
        int nl = it * 16 + grp;                 // groups write 16 consecutive nodes per step
        int node = g * 256 + hf * 128 + nl;
        if (node >= N) break;                   // monotone in it -> safe
        int c = hist[nl];
        int sl = tsum[nl] - c;
        float a0 = 0.f, a1 = 0.f, a2 = 0.f, a3 = 0.f, a4 = 0.f, a5 = 0.f, a6 = 0.f, a7 = 0.f;
        for (int i0 = 0; i0 < c; i0 += 8) {
            int cm1 = c - 1;
            int s[8]; uint4 v[8];
#pragma unroll
            for (int u = 0; u < 8; ++u) {
                int j = i0 + u; j = (j <= cm1) ? j : cm1;
                s[u] = esrc_l[sl + j];
            }
#pragma unroll
            for (int u = 0; u < 8; ++u)
                v[u] = Ab4[(size_t)s[u] * 48 + 32 + lane];
#pragma unroll
            for (int u = 0; u < 8; ++u) {
                if (i0 + u < c) {
                    a0 += BFLO(v[u].x); a1 += BFHI(v[u].x);
                    a2 += BFLO(v[u].y); a3 += BFHI(v[u].y);
                    a4 += BFLO(v[u].z); a5 += BFHI(v[u].z);
                    a6 += BFLO(v[u].w); a7 += BFHI(v[u].w);
                }
            }
        }
        union { uint4 u; bf16 hh[8]; } o;
        o.hh[0] = __float2bfloat16(a0); o.hh[1] = __float2bfloat16(a1);
        o.hh[2] = __float2bfloat16(a2); o.hh[3] = __float2bfloat16(a3);
        o.hh[4] = __float2bfloat16(a4); o.hh[5] = __float2bfloat16(a5);
        o.hh[6] = __float2bfloat16(a6); o.hh[7] = __float2bfloat16(a7);
        Ab4[(size_t)node * 48 + (size_t)r * 16 + lane] = o.u;
    }
}

// ---------------- fused GEMM1+conv-GEMM2 (LOCKED: round-1 structure) ----------------
// Benched 58.5-60us across 3 sessions; R8 session showed 77us with identical
// bytes and identical hbm_bytes (96.08MB) at proportionally lower hbm_gbps ->
// session clock-state difference, not a regression. Pipeline attempts
// R2/R3/R5 all measured 72-92us (see history). agg stride stays 136
// (272B = 17x16B: 16B-aligned for ds_read_b128; 2-way alias free per m136).

__device__ __forceinline__ void gl2lds16(const void* g, void* l) {
    __builtin_amdgcn_global_load_lds(
        (const __attribute__((address_space(1))) u32*)g,
        (__attribute__((address_space(3))) u32*)l, 16, 0, 0);
}

__global__ __launch_bounds__(256) void gemm12_kernel(const bf16* __restrict__ Ab,
                                                     const bf16* __restrict__ B1T,
                                                     const bf16* __restrict__ B2T,
                                                     const float* __restrict__ cbf,
                                                     float* __restrict__ out, int M) {
    // phase1: Ast[144][64] bf16 @0 (18432B, swizzled linear), Bst[128][64] @36736 (16384B)
    // phase2: agg[131][136] bf16 @0 (35632B, aliases Ast), Bst reused for B2T chunks
    __shared__ __align__(16) char ldsbuf[53120];
    bf16* agg = (bf16*)ldsbuf;
    char* Ast = ldsbuf;
    char* Bst = ldsbuf + 36736;

    int t = threadIdx.x;
    int lane = t & 63, wv = t >> 6;
    int r = lane & 15, qq = lane >> 4;
    int m0 = blockIdx.x * 128;
    int swz = (r & 7) << 4;                    // read-side XOR (bytes)
    int lsw = ((lane & 7) ^ (lane >> 3)) << 4; // source-side swizzled within-row byte

    int rowLo = (m0 < 8) ? 8 - m0 : 0;              // tile rows [0,rowLo) are OOB low
    int rowHi = (m0 + 136 > M) ? M - m0 + 8 : 144;  // tile rows [rowHi,144) are OOB high
    bool bdry = (rowLo > 0) || (rowHi < 144);

    const char* AbB = (const char*)Ab;
    const char* B1B = (const char*)B1T;
    const char* B2B = (const char*)B2T;

    // ---- phase 1: 144-row agg tile = Ab[m0-8 .. m0+136) @ B1T^T ----
    v4f acc[9][2] = {};
    for (int kt = 0; kt < 6; ++kt) {
        int k0b = kt * 128;                    // byte offset of this K-chunk within a row
        // 34 wave-chunks of 1024B: 18 A + 16 B; wave wv issues chunks wv, wv+4, ...
        for (int c = wv; c < 34; c += 4) {
            if (c < 18) {
                int ar = m0 - 8 + c * 8 + (lane >> 3);
                ar = ar < 0 ? 0 : (ar >= M ? M - 1 : ar);   // clamp; zero-fill below
                gl2lds16(AbB + (size_t)ar * 768 + k0b + lsw, Ast + c * 1024);
            } else {
                int row = (c - 18) * 8 + (lane >> 3);
                gl2lds16(B1B + (size_t)row * 768 + k0b + lsw, Bst + (c - 18) * 1024);
            }
        }
        __syncthreads();
        if (bdry) {   // blocks 0 and last only: zero the OOB halo rows (post-load)
            int* A4 = (int*)Ast;
            for (int i = t; i < rowLo * 32; i += 256) A4[i] = 0;
            for (int i = t; i < (144 - rowHi) * 32; i += 256) A4[rowHi * 32 + i] = 0;
            __syncthreads();
        }
#pragma unroll
        for (int ks = 0; ks < 2; ++ks) {
            int cb = (ks * 64 + qq * 16) ^ swz;
            v8s bfr[2];
#pragma unroll
            for (int tn = 0; tn < 2; ++tn)
                bfr[tn] = *(const v8s*)(Bst + (wv * 32 + tn * 16 + r) * 128 + cb);
#pragma unroll
            for (int tm = 0; tm < 9; ++tm) {
                v8s af = *(const v8s*)(Ast + (tm * 16 + r) * 128 + cb);
#pragma unroll
                for (int tn = 0; tn < 2; ++tn)
                    acc[tm][tn] = __builtin_amdgcn_mfma_f32_16x16x32_bf16(af, bfr[tn], acc[tm][tn], 0, 0, 0);
            }
        }
        __syncthreads();
    }
    // acc -> agg LDS (keep only rows 7..137; conv reads rows j+kk, j in 0..127, kk 0..2)
#pragma unroll
    for (int tm = 0; tm < 9; ++tm)
#pragma unroll
        for (int tn = 0; tn < 2; ++tn)
#pragma unroll
            for (int reg = 0; reg < 4; ++reg) {
                int row = tm * 16 + qq * 4 + reg;
                if (row >= 7 && row < 138)
                    agg[(row - 7) * 136 + wv * 32 + tn * 16 + r] =
                        __float2bfloat16(acc[tm][tn][reg]);
            }
    __syncthreads();

    // ---- phase 2: out[m0 .. m0+128) = relu(bias + sum_taps aggLDS(shifted) @ B2T^T) ----
    v4f acc2[8][2] = {};
    for (int kt = 0; kt < 6; ++kt) {
        int k0b = kt * 128;
        int kk = kt >> 1;            // conv tap 0..2
        int rem = (kt & 1) * 64;     // ci offset within tap
        for (int c = wv; c < 16; c += 4)
            gl2lds16(B2B + (size_t)(c * 8 + (lane >> 3)) * 768 + k0b + lsw, Bst + c * 1024);
        __syncthreads();
#pragma unroll
        for (int ks = 0; ks < 2; ++ks) {
            int cb = (ks * 64 + qq * 16) ^ swz;
            v8s bfr[2];
#pragma unroll
            for (int tn = 0; tn < 2; ++tn)
                bfr[tn] = *(const v8s*)(Bst + (wv * 32 + tn * 16 + r) * 128 + cb);
#pragma unroll
            for (int tm = 0; tm < 8; ++tm) {
                // out local row tm*16+m needs stored agg row tm*16+m+kk (store base = tile row 7)
                v8s af = *(const v8s*)&agg[(tm * 16 + r + kk) * 136 + rem + ks * 32 + qq * 8];
#pragma unroll
                for (int tn = 0; tn < 2; ++tn)
                    acc2[tm][tn] = __builtin_amdgcn_mfma_f32_16x16x32_bf16(af, bfr[tn], acc2[tm][tn], 0, 0, 0);
            }
        }
        __syncthreads();
    }
#pragma unroll
    for (int tm = 0; tm < 8; ++tm)
#pragma unroll
        for (int tn = 0; tn < 2; ++tn) {
            int col = wv * 32 + tn * 16 + r;
            float bias = cbf[col];
#pragma unroll
            for (int reg = 0; reg < 4; ++reg) {
                int grow = m0 + tm * 16 + qq * 4 + reg;
                if (grow < M) {
                    float v = acc2[tm][tn][reg] + bias;
                    out[(size_t)grow * 128 + col] = fmaxf(v, 0.f);
                }
            }
        }
}

// ---------------- launch ----------------

extern "C" void kernel_launch(void* const* d_in, const int* in_sizes, int n_in,
                              void* d_out, int out_size, void* d_ws, size_t ws_size,
                              hipStream_t stream) {
    const float* x     = (const float*)d_in[0];
    const int*   e0    = (const int*)d_in[1];
    const int*   e1    = (const int*)d_in[2];
    const float* Wrel  = (const float*)d_in[3];
    const float* Wself = (const float*)d_in[4];
    const float* convw = (const float*)d_in[5];
    const float* convb = (const float*)d_in[6];
    float* out = (float*)d_out;

    int N = in_sizes[0] / 128;   // 100000
    int E = in_sizes[1] / 2;     // 600000
    int nbrr = (N + 255) >> 8;   // 391 buckets per relation
    int NB = 2 * nbrr;           // 782

    char* p = (char*)d_ws;
    auto alloc = [&](size_t bytes) { char* q = p; p += (bytes + 255) & ~(size_t)255; return q; };
    int*  gcur  = (int*)alloc((size_t)MAXNB * 4);
    unsigned int* esorted = (unsigned int*)alloc((size_t)MAXNB * CAP * 4);
    bf16* Ab   = (bf16*)alloc((size_t)N * 384 * 2);   // [H0 | H1 | x_bf16]
    bf16* B1T  = (bf16*)alloc(384 * 128 * 2);
    bf16* B2T  = (bf16*)alloc(384 * 128 * 2);
    float* cbf = (float*)alloc(512);

    hipMemsetAsync(gcur, 0, (size_t)NB * 4, stream);

    int cvtBlocks = (N * 16 + 255) / 256;       // 6250 (32B/thread)
    int prepBlocks = (98432 + 255) / 256;       // 385
    int chBlocks = (2 * E + CH - 1) / CH;       // 293 (FIRST in grid)
    frontdist_kernel<<<chBlocks + cvtBlocks + prepBlocks, 256, 0, stream>>>(
        (const float4*)x, (uint4*)Ab, Wrel, Wself, convw, convb,
        B1T, B2T, cbf, e0, e1, gcur, esorted, N, E, nbrr, chBlocks, cvtBlocks);

    csrgather_kernel<<<2 * NB, 256, 0, stream>>>(esorted, gcur, (uint4*)Ab, N, nbrr);

    int mBlocks = (N + 127) / 128;
    gemm12_kernel<<<mBlocks, 256, 0, stream>>>(Ab, B1T, B2T, cbf, out, N);
}

// Round 10
// 236.869 us; speedup vs baseline: 1.0109x; 1.0109x over previous
//
#include <hip/hip_runtime.h>
#include <hip/hip_bf16.h>

typedef __hip_bfloat16 bf16;
typedef short v8s __attribute__((ext_vector_type(8)));
typedef float v4f __attribute__((ext_vector_type(4)));
typedef unsigned int u32;

#define BFLO(u) __uint_as_float((u) << 16)
#define BFHI(u) __uint_as_float((u) & 0xffff0000u)

#define CH 2048        // edges per distribute block (586 dist blocks: 2x TLP in latency phase)
#define MAXNB 800      // >= 2 * ceil(N/256) = 782
#define CAP 2048       // fixed bucket capacity: mean 1534, sigma ~39 -> 13-sigma margin

// Derive index stride in-block: int64 LE with values < 2^31 has zero odd slots.
__device__ __forceinline__ int block_stride(const int* e0, int E, int* sm) {
    int t = threadIdx.x;
    if (t == 0) *sm = 0;
    __syncthreads();
    int nz = 0;
    for (int i = t; i < 2048; i += 256) {
        int slot = 2 * i + 1;
        if (slot < 2 * E) nz |= (e0[slot] != 0);
    }
    if (nz) atomicOr(sm, 1);
    __syncthreads();
    return *sm ? 1 : 2;
}

// ---------------- fused front+dist: edge distribute (FIRST) | cvt | weight prep ----------------
// dist blocks first so their latency phase overlaps cvt's BW phase; dist uses
// two-pass LDS reserve -> direct global scatter (no scan/staging/copy loop).

__global__ __launch_bounds__(256) void frontdist_kernel(const float4* __restrict__ x4,
                                                        uint4* __restrict__ Ab4,
                                                        const float* __restrict__ Wrel,
                                                        const float* __restrict__ Wself,
                                                        const float* __restrict__ convw,
                                                        const float* __restrict__ convb,
                                                        bf16* __restrict__ B1T,
                                                        bf16* __restrict__ B2T,
                                                        float* __restrict__ cbf,
                                                        const int* __restrict__ e0,
                                                        const int* __restrict__ e1,
                                                        int* __restrict__ gcur,
                                                        unsigned int* __restrict__ esorted,
                                                        int N, int E, int nbrr,
                                                        int chBlocks, int cvtBlocks) {
    int b = blockIdx.x;
    if (b < chBlocks) {
        // ---- distribute: two-pass LDS reserve -> direct global scatter ----
        // record = src (17b) | tgt_local (8b) << 17
        __shared__ int hist[MAXNB], lcur[MAXNB], runbase[MAXNB];
        __shared__ int smf;
        int st = block_stride(e0, E, &smf);
        int NB = 2 * nbrr;
        int t = threadIdx.x;
        for (int i = t; i < NB; i += 256) { hist[i] = 0; lcur[i] = 0; }
        __syncthreads();
        long base = (long)b * CH;
        unsigned int rec[CH / 256]; short bk[CH / 256];
#pragma unroll
        for (int j = 0; j < CH / 256; ++j) {
            long e = base + j * 256 + t;
            if (e < 2 * (long)E) {
                int r = e >= E;
                long idx = r ? e - E : e;
                const int* ei = r ? e1 : e0;
                int src = ei[(size_t)idx * st];
                int tgt = ei[(size_t)(E + idx) * st];
                bk[j] = (short)(r * nbrr + (tgt >> 8));
                rec[j] = (unsigned int)src | ((unsigned int)(tgt & 255) << 17);
                atomicAdd(&hist[bk[j]], 1);
            } else bk[j] = -1;
        }
        __syncthreads();
        // reserve contiguous run per touched bucket (gcur zeroed by memset)
        for (int i = t; i < NB; i += 256)
            if (hist[i]) runbase[i] = i * CAP + atomicAdd(&gcur[i], hist[i]);
        __syncthreads();
        // direct scatter: rank within run via LDS atomic, store straight to global
#pragma unroll
        for (int j = 0; j < CH / 256; ++j) if (bk[j] >= 0) {
            int p = atomicAdd(&lcur[bk[j]], 1);
            esorted[runbase[bk[j]] + p] = rec[j];
        }
    } else if (b < chBlocks + cvtBlocks) {
        // ---- x -> bf16 into Ab cols 256:384, 32B/thread ----
        int i = (b - chBlocks) * 256 + threadIdx.x;
        if (i >= N * 16) return;
        int n = i >> 4, g2 = i & 15;
        float4 f0 = x4[2 * i], f1 = x4[2 * i + 1];
        union { uint4 u; bf16 h[8]; } o;
        o.h[0] = __float2bfloat16(f0.x); o.h[1] = __float2bfloat16(f0.y);
        o.h[2] = __float2bfloat16(f0.z); o.h[3] = __float2bfloat16(f0.w);
        o.h[4] = __float2bfloat16(f1.x); o.h[5] = __float2bfloat16(f1.y);
        o.h[6] = __float2bfloat16(f1.z); o.h[7] = __float2bfloat16(f1.w);
        Ab4[(size_t)n * 48 + 32 + g2] = o.u;
    } else {
        // ---- weight prep ----
        int i = (b - chBlocks - cvtBlocks) * 256 + threadIdx.x;
        if (i < 49152) {
            int co = i / 384, k = i % 384;
            float v;
            if (k < 128)      v = Wrel[co * 128 + k];
            else if (k < 256) v = Wrel[16384 + co * 128 + (k - 128)];
            else              v = Wself[co * 128 + (k - 256)];
            B1T[i] = __float2bfloat16(v);
        } else if (i < 98304) {
            int j = i - 49152;
            int co = j / 384, k = j % 384, kk = k >> 7, ci = k & 127;
            B2T[j] = __float2bfloat16(convw[co * 384 + ci * 3 + kk]);
        } else if (i < 98432) {
            int c = i - 98304;
            cbf[c] = convb[c];
        }
    }
}

// ---------------- fused csr+gather: per-QUARTER-bucket LDS sort -> direct gather-reduce ----------------
// R9 counters: 59.5us, occupancy 48%, VALU 24.6%, 0 MFMA -> still latency-
// bound (serial chain 8 nodes/group, 6.1 blocks/CU). Quarter split: 64 nodes
// per block, grid 3128 (~12/CU dispatch), serial chain 4 nodes/group, 64-bin
// sort. Each quarter-block scans the full bucket list (L2/L3-hot, +~29MB)
// and filters by tgt_local>>6 with atomic compaction.

__global__ __launch_bounds__(256) void csrgather_kernel(const unsigned int* __restrict__ esorted,
                                                        const int* __restrict__ gcur,
                                                        uint4* __restrict__ Ab4, int N, int nbrr) {
    __shared__ unsigned int rec_l[CAP];
    __shared__ int esrc_l[CAP];
    __shared__ int hist[64], lcur[64], tsum[256];
    __shared__ int nloc;
    int b = blockIdx.x;           // b = bucket*4 + quarter
    int bb = b >> 2, qt = b & 3;
    int r = bb >= nbrr;
    int g = r ? bb - nbrr : bb;
    int t = threadIdx.x;
    int s0 = bb * CAP;
    int ne = gcur[bb]; ne = (ne > CAP) ? CAP : ne;
    if (t < 64) hist[t] = 0;
    if (t == 0) nloc = 0;
    __syncthreads();
    // filter + compact this quarter's records; histogram 64 bins
    for (int i = t; i < ne; i += 256) {
        unsigned int rec = esorted[s0 + i];
        int tl = (rec >> 17) & 255;
        if ((tl >> 6) == qt) {
            int p = atomicAdd(&nloc, 1);
            rec_l[p] = rec;
            atomicAdd(&hist[tl & 63], 1);
        }
    }
    __syncthreads();
    int nh = nloc;
    int h = (t < 64) ? hist[t] : 0;
    tsum[t] = h; __syncthreads();
    for (int d = 1; d < 64; d <<= 1) {
        int add = (t >= d) ? tsum[t - d] : 0;
        __syncthreads(); tsum[t] += add; __syncthreads();
    }
    if (t < 64) lcur[t] = tsum[t] - h;   // exclusive start
    __syncthreads();
    for (int i = t; i < nh; i += 256) {
        unsigned int rec = rec_l[i];
        int p = atomicAdd(&lcur[(rec >> 17) & 63], 1);
        esrc_l[p] = rec & 0x1FFFF;
    }
    __syncthreads();
    // gather: 16-lane group per node, 4 nodes per group, unroll-8 uint4 rows
    int grp = t >> 4, lane = t & 15;
    for (int it = 0; it < 4; ++it) {
        int nl = it * 16 + grp;                 // groups write 16 consecutive nodes per step
        int node = g * 256 + qt * 64 + nl;
        if (node >= N) break;                   // monotone in it -> safe
        int c = hist[nl];
        int sl = tsum[nl] - c;
        float a0 = 0.f, a1 = 0.f, a2 = 0.f, a3 = 0.f, a4 = 0.f, a5 = 0.f, a6 = 0.f, a7 = 0.f;
        for (int i0 = 0; i0 < c; i0 += 8) {
            int cm1 = c - 1;
            int s[8]; uint4 v[8];
#pragma unroll
            for (int u = 0; u < 8; ++u) {
                int j = i0 + u; j = (j <= cm1) ? j : cm1;
                s[u] = esrc_l[sl + j];
            }
#pragma unroll
            for (int u = 0; u < 8; ++u)
                v[u] = Ab4[(size_t)s[u] * 48 + 32 + lane];
#pragma unroll
            for (int u = 0; u < 8; ++u) {
                if (i0 + u < c) {
                    a0 += BFLO(v[u].x); a1 += BFHI(v[u].x);
                    a2 += BFLO(v[u].y); a3 += BFHI(v[u].y);
                    a4 += BFLO(v[u].z); a5 += BFHI(v[u].z);
                    a6 += BFLO(v[u].w); a7 += BFHI(v[u].w);
                }
            }
        }
        union { uint4 u; bf16 hh[8]; } o;
        o.hh[0] = __float2bfloat16(a0); o.hh[1] = __float2bfloat16(a1);
        o.hh[2] = __float2bfloat16(a2); o.hh[3] = __float2bfloat16(a3);
        o.hh[4] = __float2bfloat16(a4); o.hh[5] = __float2bfloat16(a5);
        o.hh[6] = __float2bfloat16(a6); o.hh[7] = __float2bfloat16(a7);
        Ab4[(size_t)node * 48 + (size_t)r * 16 + lane] = o.u;
    }
}

// ---------------- fused GEMM1+conv-GEMM2 (LOCKED: round-1 structure) ----------------
// Benched 58.5-60us across 4 sessions (R8's 77 = slow clocks, identical
// hbm_bytes). Pipeline attempts R2/R3/R5 all measured 72-92us. agg stride
// stays 136 (272B = 17x16B: 16B-aligned for ds_read_b128; 2-way alias free).

__device__ __forceinline__ void gl2lds16(const void* g, void* l) {
    __builtin_amdgcn_global_load_lds(
        (const __attribute__((address_space(1))) u32*)g,
        (__attribute__((address_space(3))) u32*)l, 16, 0, 0);
}

__global__ __launch_bounds__(256) void gemm12_kernel(const bf16* __restrict__ Ab,
                                                     const bf16* __restrict__ B1T,
                                                     const bf16* __restrict__ B2T,
                                                     const float* __restrict__ cbf,
                                                     float* __restrict__ out, int M) {
    // phase1: Ast[144][64] bf16 @0 (18432B, swizzled linear), Bst[128][64] @36736 (16384B)
    // phase2: agg[131][136] bf16 @0 (35632B, aliases Ast), Bst reused for B2T chunks
    __shared__ __align__(16) char ldsbuf[53120];
    bf16* agg = (bf16*)ldsbuf;
    char* Ast = ldsbuf;
    char* Bst = ldsbuf + 36736;

    int t = threadIdx.x;
    int lane = t & 63, wv = t >> 6;
    int r = lane & 15, qq = lane >> 4;
    int m0 = blockIdx.x * 128;
    int swz = (r & 7) << 4;                    // read-side XOR (bytes)
    int lsw = ((lane & 7) ^ (lane >> 3)) << 4; // source-side swizzled within-row byte

    int rowLo = (m0 < 8) ? 8 - m0 : 0;              // tile rows [0,rowLo) are OOB low
    int rowHi = (m0 + 136 > M) ? M - m0 + 8 : 144;  // tile rows [rowHi,144) are OOB high
    bool bdry = (rowLo > 0) || (rowHi < 144);

    const char* AbB = (const char*)Ab;
    const char* B1B = (const char*)B1T;
    const char* B2B = (const char*)B2T;

    // ---- phase 1: 144-row agg tile = Ab[m0-8 .. m0+136) @ B1T^T ----
    v4f acc[9][2] = {};
    for (int kt = 0; kt < 6; ++kt) {
        int k0b = kt * 128;                    // byte offset of this K-chunk within a row
        // 34 wave-chunks of 1024B: 18 A + 16 B; wave wv issues chunks wv, wv+4, ...
        for (int c = wv; c < 34; c += 4) {
            if (c < 18) {
                int ar = m0 - 8 + c * 8 + (lane >> 3);
                ar = ar < 0 ? 0 : (ar >= M ? M - 1 : ar);   // clamp; zero-fill below
                gl2lds16(AbB + (size_t)ar * 768 + k0b + lsw, Ast + c * 1024);
            } else {
                int row = (c - 18) * 8 + (lane >> 3);
                gl2lds16(B1B + (size_t)row * 768 + k0b + lsw, Bst + (c - 18) * 1024);
            }
        }
        __syncthreads();
        if (bdry) {   // blocks 0 and last only: zero the OOB halo rows (post-load)
            int* A4 = (int*)Ast;
            for (int i = t; i < rowLo * 32; i += 256) A4[i] = 0;
            for (int i = t; i < (144 - rowHi) * 32; i += 256) A4[rowHi * 32 + i] = 0;
            __syncthreads();
        }
#pragma unroll
        for (int ks = 0; ks < 2; ++ks) {
            int cb = (ks * 64 + qq * 16) ^ swz;
            v8s bfr[2];
#pragma unroll
            for (int tn = 0; tn < 2; ++tn)
                bfr[tn] = *(const v8s*)(Bst + (wv * 32 + tn * 16 + r) * 128 + cb);
#pragma unroll
            for (int tm = 0; tm < 9; ++tm) {
                v8s af = *(const v8s*)(Ast + (tm * 16 + r) * 128 + cb);
#pragma unroll
                for (int tn = 0; tn < 2; ++tn)
                    acc[tm][tn] = __builtin_amdgcn_mfma_f32_16x16x32_bf16(af, bfr[tn], acc[tm][tn], 0, 0, 0);
            }
        }
        __syncthreads();
    }
    // acc -> agg LDS (keep only rows 7..137; conv reads rows j+kk, j in 0..127, kk 0..2)
#pragma unroll
    for (int tm = 0; tm < 9; ++tm)
#pragma unroll
        for (int tn = 0; tn < 2; ++tn)
#pragma unroll
            for (int reg = 0; reg < 4; ++reg) {
                int row = tm * 16 + qq * 4 + reg;
                if (row >= 7 && row < 138)
                    agg[(row - 7) * 136 + wv * 32 + tn * 16 + r] =
                        __float2bfloat16(acc[tm][tn][reg]);
            }
    __syncthreads();

    // ---- phase 2: out[m0 .. m0+128) = relu(bias + sum_taps aggLDS(shifted) @ B2T^T) ----
    v4f acc2[8][2] = {};
    for (int kt = 0; kt < 6; ++kt) {
        int k0b = kt * 128;
        int kk = kt >> 1;            // conv tap 0..2
        int rem = (kt & 1) * 64;     // ci offset within tap
        for (int c = wv; c < 16; c += 4)
            gl2lds16(B2B + (size_t)(c * 8 + (lane >> 3)) * 768 + k0b + lsw, Bst + c * 1024);
        __syncthreads();
#pragma unroll
        for (int ks = 0; ks < 2; ++ks) {
            int cb = (ks * 64 + qq * 16) ^ swz;
            v8s bfr[2];
#pragma unroll
            for (int tn = 0; tn < 2; ++tn)
                bfr[tn] = *(const v8s*)(Bst + (wv * 32 + tn * 16 + r) * 128 + cb);
#pragma unroll
            for (int tm = 0; tm < 8; ++tm) {
                // out local row tm*16+m needs stored agg row tm*16+m+kk (store base = tile row 7)
                v8s af = *(const v8s*)&agg[(tm * 16 + r + kk) * 136 + rem + ks * 32 + qq * 8];
#pragma unroll
                for (int tn = 0; tn < 2; ++tn)
                    acc2[tm][tn] = __builtin_amdgcn_mfma_f32_16x16x32_bf16(af, bfr[tn], acc2[tm][tn], 0, 0, 0);
            }
        }
        __syncthreads();
    }
#pragma unroll
    for (int tm = 0; tm < 8; ++tm)
#pragma unroll
        for (int tn = 0; tn < 2; ++tn) {
            int col = wv * 32 + tn * 16 + r;
            float bias = cbf[col];
#pragma unroll
            for (int reg = 0; reg < 4; ++reg) {
                int grow = m0 + tm * 16 + qq * 4 + reg;
                if (grow < M) {
                    float v = acc2[tm][tn][reg] + bias;
                    out[(size_t)grow * 128 + col] = fmaxf(v, 0.f);
                }
            }
        }
}

// ---------------- launch ----------------

extern "C" void kernel_launch(void* const* d_in, const int* in_sizes, int n_in,
                              void* d_out, int out_size, void* d_ws, size_t ws_size,
                              hipStream_t stream) {
    const float* x     = (const float*)d_in[0];
    const int*   e0    = (const int*)d_in[1];
    const int*   e1    = (const int*)d_in[2];
    const float* Wrel  = (const float*)d_in[3];
    const float* Wself = (const float*)d_in[4];
    const float* convw = (const float*)d_in[5];
    const float* convb = (const float*)d_in[6];
    float* out = (float*)d_out;

    int N = in_sizes[0] / 128;   // 100000
    int E = in_sizes[1] / 2;     // 600000
    int nbrr = (N + 255) >> 8;   // 391 buckets per relation
    int NB = 2 * nbrr;           // 782

    char* p = (char*)d_ws;
    auto alloc = [&](size_t bytes) { char* q = p; p += (bytes + 255) & ~(size_t)255; return q; };
    int*  gcur  = (int*)alloc((size_t)MAXNB * 4);
    unsigned int* esorted = (unsigned int*)alloc((size_t)MAXNB * CAP * 4);
    bf16* Ab   = (bf16*)alloc((size_t)N * 384 * 2);   // [H0 | H1 | x_bf16]
    bf16* B1T  = (bf16*)alloc(384 * 128 * 2);
    bf16* B2T  = (bf16*)alloc(384 * 128 * 2);
    float* cbf = (float*)alloc(512);

    hipMemsetAsync(gcur, 0, (size_t)NB * 4, stream);

    int cvtBlocks = (N * 16 + 255) / 256;       // 6250 (32B/thread)
    int prepBlocks = (98432 + 255) / 256;       // 385
    int chBlocks = (2 * E + CH - 1) / CH;       // 586 (FIRST in grid)
    frontdist_kernel<<<chBlocks + cvtBlocks + prepBlocks, 256, 0, stream>>>(
        (const float4*)x, (uint4*)Ab, Wrel, Wself, convw, convb,
        B1T, B2T, cbf, e0, e1, gcur, esorted, N, E, nbrr, chBlocks, cvtBlocks);

    csrgather_kernel<<<4 * NB, 256, 0, stream>>>(esorted, gcur, (uint4*)Ab, N, nbrr);

    int mBlocks = (N + 127) / 128;
    gemm12_kernel<<<mBlocks, 256, 0, stream>>>(Ab, B1T, B2T, cbf, out, N);
}